// Round 1
// baseline (98.166 us; speedup 1.0000x reference)
//
#include <hip/hip_runtime.h>

// LogLinearCDE: out = softmax(W_out @ (y0 * prod_l flows[l]) + b_out)
// flows[l,h] = 1 + sum_c logsigs[l,c]*vf_A[c,h];  y0 = W_in@x0 + b_in
// Only the FINAL hidden state matters -> product over L, chunked in parallel.

#define LSTEPS 16384
#define HID    4096
#define CC     17
#define DD     16
#define NLAB   10
#define TPB    256
#define HP     4                      // columns per thread
#define HBLOCKS (HID/(TPB*HP))        // 4 column-blocks

__global__ __launch_bounds__(TPB) void partial_kernel(
    const float* __restrict__ logsigs, const float* __restrict__ vfA,
    float* __restrict__ ws_p, int chunk_rows) {
  const int hb    = blockIdx.x;       // column block 0..HBLOCKS-1
  const int chunk = blockIdx.y;       // L-chunk
  const int h0    = hb * (TPB*HP) + threadIdx.x;

  // per-thread vf_A fragment: HP columns x CC coeffs (static-indexed -> regs)
  float a[HP][CC];
  #pragma unroll
  for (int c = 0; c < CC; ++c) {
    #pragma unroll
    for (int j = 0; j < HP; ++j)
      a[j][c] = vfA[c*HID + h0 + j*TPB];
  }

  float p[HP];
  #pragma unroll
  for (int j = 0; j < HP; ++j) p[j] = 1.0f;

  const float* __restrict__ row = logsigs + (size_t)chunk * chunk_rows * CC;
  for (int r = 0; r < chunk_rows; ++r) {
    // wave-uniform row of 17 logsig coeffs (scalar/broadcast loads)
    float ls[CC];
    #pragma unroll
    for (int c = 0; c < CC; ++c) ls[c] = row[c];
    row += CC;
    #pragma unroll
    for (int j = 0; j < HP; ++j) {
      float f = fmaf(ls[0], a[j][0], 1.0f);
      #pragma unroll
      for (int c = 1; c < CC; ++c) f = fmaf(ls[c], a[j][c], f);
      p[j] *= f;
    }
  }
  #pragma unroll
  for (int j = 0; j < HP; ++j)
    ws_p[(size_t)chunk*HID + h0 + j*TPB] = p[j];
}

__global__ __launch_bounds__(256) void reduce_kernel(
    const float* __restrict__ ws_p, const float* __restrict__ Win,
    const float* __restrict__ bin,  const float* __restrict__ x0,
    float* __restrict__ ws_y, int nchunk) {
  const int h = blockIdx.x*256 + threadIdx.x;
  float y = bin[h];
  #pragma unroll
  for (int d = 0; d < DD; ++d) y = fmaf(Win[h*DD + d], x0[d], y);
  float p = 1.0f;
  for (int k = 0; k < nchunk; ++k) p *= ws_p[(size_t)k*HID + h];
  ws_y[h] = y * p;
}

__global__ __launch_bounds__(256) void head_kernel(
    const float* __restrict__ ws_y, const float* __restrict__ Wout,
    const float* __restrict__ bout, float* __restrict__ out) {
  const int tid = threadIdx.x;
  float acc[NLAB];
  #pragma unroll
  for (int j = 0; j < NLAB; ++j) acc[j] = 0.0f;
  for (int h = tid; h < HID; h += 256) {
    const float y = ws_y[h];
    #pragma unroll
    for (int j = 0; j < NLAB; ++j) acc[j] = fmaf(Wout[j*HID + h], y, acc[j]);
  }
  // wave reduce (64 lanes)
  #pragma unroll
  for (int j = 0; j < NLAB; ++j) {
    #pragma unroll
    for (int off = 32; off > 0; off >>= 1)
      acc[j] += __shfl_down(acc[j], off);
  }
  __shared__ float sm[4][NLAB];
  const int wave = tid >> 6, lane = tid & 63;
  if (lane == 0) {
    #pragma unroll
    for (int j = 0; j < NLAB; ++j) sm[wave][j] = acc[j];
  }
  __syncthreads();
  if (tid == 0) {
    float logits[NLAB];
    #pragma unroll
    for (int j = 0; j < NLAB; ++j)
      logits[j] = bout[j] + sm[0][j] + sm[1][j] + sm[2][j] + sm[3][j];
    float m = logits[0];
    #pragma unroll
    for (int j = 1; j < NLAB; ++j) m = fmaxf(m, logits[j]);
    float s = 0.0f;
    #pragma unroll
    for (int j = 0; j < NLAB; ++j) { logits[j] = __expf(logits[j] - m); s += logits[j]; }
    const float inv = 1.0f / s;
    #pragma unroll
    for (int j = 0; j < NLAB; ++j) out[j] = logits[j] * inv;
  }
}

extern "C" void kernel_launch(void* const* d_in, const int* in_sizes, int n_in,
                              void* d_out, int out_size, void* d_ws, size_t ws_size,
                              hipStream_t stream) {
  // inputs: 0=ts (unused), 1=logsigs (L,C), 2=x0 (D), 3=W_in (H,D), 4=b_in (H),
  //         5=vf_A (C,H), 6=W_out (10,H), 7=b_out (10)
  const float* logsigs = (const float*)d_in[1];
  const float* x0      = (const float*)d_in[2];
  const float* Win     = (const float*)d_in[3];
  const float* bin     = (const float*)d_in[4];
  const float* vfA     = (const float*)d_in[5];
  const float* Wout    = (const float*)d_in[6];
  const float* bout    = (const float*)d_in[7];
  float* out = (float*)d_out;

  // pick nchunk to fit workspace: nchunk*H partials + H final
  int nchunk = 256;
  while (nchunk > 1 && (size_t)(nchunk + 1) * HID * sizeof(float) > ws_size)
    nchunk >>= 1;
  const int chunk_rows = LSTEPS / nchunk;

  float* ws_p = (float*)d_ws;
  float* ws_y = ws_p + (size_t)nchunk * HID;

  partial_kernel<<<dim3(HBLOCKS, nchunk), TPB, 0, stream>>>(logsigs, vfA, ws_p, chunk_rows);
  reduce_kernel<<<HID/256, 256, 0, stream>>>(ws_p, Win, bin, x0, ws_y, nchunk);
  head_kernel<<<1, 256, 0, stream>>>(ws_y, Wout, bout, out);
}

// Round 2
// 41.310 us; speedup vs baseline: 2.3763x; 2.3763x over previous
//
#include <hip/hip_runtime.h>

// LogLinearCDE: out = softmax(W_out @ (y0 * prod_l flows[l]) + b_out)
// flows[l,h] = 1 + sum_c logsigs[l,c]*vf_A[c,h];  y0 = W_in@x0 + b_in
// Only the FINAL hidden state matters -> product over L, chunked tree-reduce.

#define LSTEPS 16384
#define HID    4096
#define CC     17
#define DD     16
#define NLAB   10
#define TPB    256
#define HP     4                      // columns per thread
#define HBLOCKS (HID/(TPB*HP))        // 4 column-blocks

__global__ __launch_bounds__(TPB) void partial_kernel(
    const float* __restrict__ logsigs, const float* __restrict__ vfA,
    float* __restrict__ ws_p, int chunk_rows) {
  const int hb    = blockIdx.x;       // column block 0..HBLOCKS-1
  const int chunk = blockIdx.y;       // L-chunk
  const int h0    = hb * (TPB*HP) + threadIdx.x;

  // per-thread vf_A fragment: HP columns x CC coeffs (static-indexed -> regs)
  float a[HP][CC];
  #pragma unroll
  for (int c = 0; c < CC; ++c) {
    #pragma unroll
    for (int j = 0; j < HP; ++j)
      a[j][c] = vfA[c*HID + h0 + j*TPB];
  }

  float p[HP];
  #pragma unroll
  for (int j = 0; j < HP; ++j) p[j] = 1.0f;

  const float* __restrict__ row = logsigs + (size_t)chunk * chunk_rows * CC;
  #pragma unroll 2
  for (int r = 0; r < chunk_rows; ++r) {
    // wave-uniform row of 17 logsig coeffs (scalarized to s_load)
    float ls[CC];
    #pragma unroll
    for (int c = 0; c < CC; ++c) ls[c] = row[c];
    row += CC;
    #pragma unroll
    for (int j = 0; j < HP; ++j) {
      float f = fmaf(ls[0], a[j][0], 1.0f);
      #pragma unroll
      for (int c = 1; c < CC; ++c) f = fmaf(ls[c], a[j][c], f);
      p[j] *= f;
    }
  }
  #pragma unroll
  for (int j = 0; j < HP; ++j)
    ws_p[(size_t)chunk*HID + h0 + j*TPB] = p[j];
}

// stage A: product over cpg chunks per group; grid (HID/256, groups)
__global__ __launch_bounds__(256) void groupred_kernel(
    const float* __restrict__ ws_p, float* __restrict__ ws_g, int cpg) {
  const int h = blockIdx.x*256 + threadIdx.x;
  const int g = blockIdx.y;
  const float* __restrict__ base = ws_p + (size_t)g*cpg*HID + h;
  float p = 1.0f;
  #pragma unroll 4
  for (int k = 0; k < cpg; ++k) p *= base[(size_t)k*HID];
  ws_g[(size_t)g*HID + h] = p;
}

// stage B: product over groups, fused with y0 = W_in@x0 + b_in
__global__ __launch_bounds__(256) void finalred_kernel(
    const float* __restrict__ ws_g, const float* __restrict__ Win,
    const float* __restrict__ bin,  const float* __restrict__ x0,
    float* __restrict__ ws_y, int groups) {
  const int h = blockIdx.x*256 + threadIdx.x;
  float p = 1.0f;
  #pragma unroll 4
  for (int g = 0; g < groups; ++g) p *= ws_g[(size_t)g*HID + h];
  // y0: W_in row h is 16 contiguous floats (64B aligned) -> 4x float4
  const float4* __restrict__ wrow = reinterpret_cast<const float4*>(Win + (size_t)h*DD);
  float y = bin[h];
  #pragma unroll
  for (int q = 0; q < DD/4; ++q) {
    float4 w = wrow[q];
    y = fmaf(w.x, x0[q*4+0], y);
    y = fmaf(w.y, x0[q*4+1], y);
    y = fmaf(w.z, x0[q*4+2], y);
    y = fmaf(w.w, x0[q*4+3], y);
  }
  ws_y[h] = y * p;
}

__global__ __launch_bounds__(256) void head_kernel(
    const float* __restrict__ ws_y, const float* __restrict__ Wout,
    const float* __restrict__ bout, float* __restrict__ out) {
  const int tid = threadIdx.x;
  float acc[NLAB];
  #pragma unroll
  for (int j = 0; j < NLAB; ++j) acc[j] = 0.0f;
  for (int h = tid; h < HID; h += 256) {
    const float y = ws_y[h];
    #pragma unroll
    for (int j = 0; j < NLAB; ++j) acc[j] = fmaf(Wout[j*HID + h], y, acc[j]);
  }
  // wave reduce (64 lanes)
  #pragma unroll
  for (int j = 0; j < NLAB; ++j) {
    #pragma unroll
    for (int off = 32; off > 0; off >>= 1)
      acc[j] += __shfl_down(acc[j], off);
  }
  __shared__ float sm[4][NLAB];
  const int wave = tid >> 6, lane = tid & 63;
  if (lane == 0) {
    #pragma unroll
    for (int j = 0; j < NLAB; ++j) sm[wave][j] = acc[j];
  }
  __syncthreads();
  if (tid == 0) {
    float logits[NLAB];
    #pragma unroll
    for (int j = 0; j < NLAB; ++j)
      logits[j] = bout[j] + sm[0][j] + sm[1][j] + sm[2][j] + sm[3][j];
    float m = logits[0];
    #pragma unroll
    for (int j = 1; j < NLAB; ++j) m = fmaxf(m, logits[j]);
    float s = 0.0f;
    #pragma unroll
    for (int j = 0; j < NLAB; ++j) { logits[j] = __expf(logits[j] - m); s += logits[j]; }
    const float inv = 1.0f / s;
    #pragma unroll
    for (int j = 0; j < NLAB; ++j) out[j] = logits[j] * inv;
  }
}

extern "C" void kernel_launch(void* const* d_in, const int* in_sizes, int n_in,
                              void* d_out, int out_size, void* d_ws, size_t ws_size,
                              hipStream_t stream) {
  // inputs: 0=ts (unused), 1=logsigs (L,C), 2=x0 (D), 3=W_in (H,D), 4=b_in (H),
  //         5=vf_A (C,H), 6=W_out (10,H), 7=b_out (10)
  const float* logsigs = (const float*)d_in[1];
  const float* x0      = (const float*)d_in[2];
  const float* Win     = (const float*)d_in[3];
  const float* bin     = (const float*)d_in[4];
  const float* vfA     = (const float*)d_in[5];
  const float* Wout    = (const float*)d_in[6];
  const float* bout    = (const float*)d_in[7];
  float* out = (float*)d_out;

  // workspace: nchunk*H partials + groups*H group-products + H final
  int nchunk = 256;
  while (nchunk > 1 && (size_t)(nchunk + 17) * HID * sizeof(float) > ws_size)
    nchunk >>= 1;
  const int chunk_rows = LSTEPS / nchunk;
  const int groups = (nchunk >= 16) ? 16 : nchunk;
  const int cpg = nchunk / groups;

  float* ws_p = (float*)d_ws;
  float* ws_g = ws_p + (size_t)nchunk * HID;
  float* ws_y = ws_g + (size_t)16 * HID;

  partial_kernel<<<dim3(HBLOCKS, nchunk), TPB, 0, stream>>>(logsigs, vfA, ws_p, chunk_rows);
  groupred_kernel<<<dim3(HID/256, groups), 256, 0, stream>>>(ws_p, ws_g, cpg);
  finalred_kernel<<<HID/256, 256, 0, stream>>>(ws_g, Win, bin, x0, ws_y, groups);
  head_kernel<<<1, 256, 0, stream>>>(ws_y, Wout, bout, out);
}